// Round 4
// baseline (24580.029 us; speedup 1.0000x reference)
//
#include <hip/hip_runtime.h>
#include <cstddef>

#define BB 64      // batch
#define TT 512     // time steps
#define NN 250     // useful input features (alpha=1.0 block is zero)
#define HH 512     // hidden
#define NB (NN*BB) // 16000 floats per timestep slice
#define HB (HH*BB) // 32768 floats per hidden state
#define K0 762     // layer0 dot length: 250 feats + 512 recurrent
#define K1 1024    // layer1 dot length: 512 input + 512 recurrent

__device__ __forceinline__ float sigmoidf_(float x) { return 1.0f / (1.0f + expf(-x)); }

// ---------------- transpose x[b][t][n] -> xT[t][n][b] ----------------
__global__ __launch_bounds__(256) void k_transpose(const float* __restrict__ x,
                                                   float* __restrict__ xT) {
    const int t = blockIdx.x;
    const int n = blockIdx.y * 4 + (threadIdx.x >> 6);
    const int b = threadIdx.x & 63;
    if (n < NN)
        xT[(size_t)t * NB + n * BB + b] = x[(size_t)b * (TT * NN) + t * NN + n];
}

// ---------------- w[d] = (d+1e-6)^-0.5, rowsum[t] = sum_{d=1..t} w[d] ----------------
__global__ __launch_bounds__(512) void k_wrow(float* __restrict__ w, float* __restrict__ rowsum) {
    __shared__ float sw[TT];
    const int d = threadIdx.x;
    const float wd = (d >= 1) ? (1.0f / sqrtf((float)d + 1e-6f)) : 0.0f;
    sw[d] = wd;
    w[d] = wd;
    __syncthreads();
    float s = 0.0f;
    for (int j = 1; j <= d; ++j) s += sw[j];
    rowsum[d] = s;
}

// ---------------- caputo: featsT[t][n][b] = coef*(x*rowsum[t] - sum_{j<t} w[t-j]*x[j]) ----
__global__ __launch_bounds__(256) void k_caputo(const float* __restrict__ xT,
                                                const float* __restrict__ w,
                                                const float* __restrict__ rowsum,
                                                float* __restrict__ featsT) {
    const float COEF = 0.5641895835477563f;  // 1/gamma(0.5)
    const int t0 = blockIdx.x * 4;
    const int nb0 = blockIdx.y * 1024 + threadIdx.x;
    float acc[4][4];
#pragma unroll
    for (int a = 0; a < 4; ++a)
#pragma unroll
        for (int e = 0; e < 4; ++e) acc[a][e] = 0.0f;

    for (int j = 0; j < t0; ++j) {
        const float* xj = xT + (size_t)j * NB;
        const float wt0 = w[t0 - j];
        const float wt1 = w[t0 + 1 - j];
        const float wt2 = w[t0 + 2 - j];
        const float wt3 = w[t0 + 3 - j];
#pragma unroll
        for (int e = 0; e < 4; ++e) {
            const int nb = nb0 + e * 256;
            const float xv = (nb < NB) ? xj[nb] : 0.0f;
            acc[0][e] = fmaf(wt0, xv, acc[0][e]);
            acc[1][e] = fmaf(wt1, xv, acc[1][e]);
            acc[2][e] = fmaf(wt2, xv, acc[2][e]);
            acc[3][e] = fmaf(wt3, xv, acc[3][e]);
        }
    }
#pragma unroll
    for (int dj = 0; dj < 3; ++dj) {
        const int j = t0 + dj;
        const float* xj = xT + (size_t)j * NB;
#pragma unroll
        for (int e = 0; e < 4; ++e) {
            const int nb = nb0 + e * 256;
            const float xv = (nb < NB) ? xj[nb] : 0.0f;
#pragma unroll
            for (int tt = 0; tt < 4; ++tt)
                if (tt > dj) acc[tt][e] = fmaf(w[tt - dj], xv, acc[tt][e]);
        }
    }
#pragma unroll
    for (int tt = 0; tt < 4; ++tt) {
        const int t = t0 + tt;
        const float rs = rowsum[t];
        const float* xt = xT + (size_t)t * NB;
        float* ft = featsT + (size_t)t * NB;
#pragma unroll
        for (int e = 0; e < 4; ++e) {
            const int nb = nb0 + e * 256;
            if (nb < NB) ft[nb] = COEF * fmaf(xt[nb], rs, -acc[tt][e]);
        }
    }
}

// ---------------- weight transpose: WT[bi][k][r], r = hu_local*4 + gate ----------------
__global__ __launch_bounds__(256) void k_wt(const float* __restrict__ Wih0,
                                            const float* __restrict__ Whh0,
                                            const float* __restrict__ Wih1,
                                            const float* __restrict__ Whh1,
                                            float* __restrict__ WT0b,
                                            float* __restrict__ WT1b) {
    const int total0 = 128 * K0 * 16;
    const int total1 = 128 * K1 * 16;
    const int stride = gridDim.x * 256;
    for (int idx = blockIdx.x * 256 + threadIdx.x; idx < total0; idx += stride) {
        const int r = idx & 15;
        const int k = (idx >> 4) % K0;
        const int bi = idx / (16 * K0);
        const int row = (r & 3) * HH + bi * 4 + (r >> 2);
        WT0b[idx] = (k < NN) ? Wih0[(size_t)row * 500 + k] : Whh0[(size_t)row * HH + (k - NN)];
    }
    for (int idx = blockIdx.x * 256 + threadIdx.x; idx < total1; idx += stride) {
        const int r = idx & 15;
        const int k = (idx >> 4) % K1;
        const int bi = idx / (16 * K1);
        const int row = (r & 3) * HH + bi * 4 + (r >> 2);
        WT1b[idx] = (k < HH) ? Wih1[(size_t)row * HH + k] : Whh1[(size_t)row * HH + (k - HH)];
    }
}

// ---------------- persistent LSTM: all 513 wavefront steps in one launch ----------------
// blocks 0..127: layer0 unit-group bi (4 units); blocks 128..255: layer1.
// Weights staged in LDS ONCE. Grid barrier between steps (2-level sense-reversing).
#define AGENT __HIP_MEMORY_SCOPE_AGENT

__global__ __launch_bounds__(1024, 4) void k_persist(
    const float* __restrict__ featsT,
    const float* __restrict__ WT0b, const float* __restrict__ WT1b,
    const float* __restrict__ bih0, const float* __restrict__ bhh0,
    const float* __restrict__ bih1, const float* __restrict__ bhh1,
    float* __restrict__ h0T, float* __restrict__ c0T,
    float* __restrict__ h1T, float* __restrict__ c1T,
    unsigned* __restrict__ bar) {
    __shared__ float wlds[16384];       // 64KB weight slice
    __shared__ float part[16384];       // 64KB partials [wave][row][lane]
    const int tid = threadIdx.x;
    const int b = tid & 63;
    const int wv = tid >> 6;
    const int bid = blockIdx.x;
    const bool isL1 = (bid >= 128);
    const int bi = isL1 ? (bid - 128) : bid;

    // barrier pointers: leaf[g] @ bar[g*32], ggen[g] @ bar[1024+g*32], root @ bar[2048], gen @ bar[2080]
    unsigned* leaf = bar + (bid >> 3) * 32;
    unsigned* ggen = bar + 1024 + (bid >> 3) * 32;
    unsigned* root = bar + 2048;
    unsigned* gen  = bar + 2080;

    // ---- stage weights into LDS once ----
    {
        const float* __restrict__ wsrc = isL1 ? (WT1b + (size_t)bi * (K1 * 16))
                                              : (WT0b + (size_t)bi * (K0 * 16));
        const int nflt = (isL1 ? K1 : K0) * 16;
        for (int i = tid * 4; i < nflt; i += 4096)
            *reinterpret_cast<float4*>(&wlds[i]) = *reinterpret_cast<const float4*>(wsrc + i);
    }
    // ---- hoist bias sums ----
    float bsum[4] = {0.f, 0.f, 0.f, 0.f};
    if (wv < 4) {
        const int hu = bi * 4 + wv;
        const float* __restrict__ bi_ = isL1 ? bih1 : bih0;
        const float* __restrict__ bh_ = isL1 ? bhh1 : bhh0;
#pragma unroll
        for (int g = 0; g < 4; ++g) bsum[g] = bi_[g * HH + hu] + bh_[g * HH + hu];
    }
    __syncthreads();

#define FMA16(KIDX, VV)                                                         \
    {                                                                           \
        const float4* wl = reinterpret_cast<const float4*>(&wlds[(KIDX) * 16]); \
        const float4 w0_ = wl[0], w1_ = wl[1], w2_ = wl[2], w3_ = wl[3];        \
        acc[0] = fmaf(w0_.x, (VV), acc[0]);   acc[1] = fmaf(w0_.y, (VV), acc[1]);  \
        acc[2] = fmaf(w0_.z, (VV), acc[2]);   acc[3] = fmaf(w0_.w, (VV), acc[3]);  \
        acc[4] = fmaf(w1_.x, (VV), acc[4]);   acc[5] = fmaf(w1_.y, (VV), acc[5]);  \
        acc[6] = fmaf(w1_.z, (VV), acc[6]);   acc[7] = fmaf(w1_.w, (VV), acc[7]);  \
        acc[8] = fmaf(w2_.x, (VV), acc[8]);   acc[9] = fmaf(w2_.y, (VV), acc[9]);  \
        acc[10] = fmaf(w2_.z, (VV), acc[10]); acc[11] = fmaf(w2_.w, (VV), acc[11]); \
        acc[12] = fmaf(w3_.x, (VV), acc[12]); acc[13] = fmaf(w3_.y, (VV), acc[13]); \
        acc[14] = fmaf(w3_.z, (VV), acc[14]); acc[15] = fmaf(w3_.w, (VV), acc[15]); \
    }

    for (int s = 0; s <= TT; ++s) {
        const bool active = isL1 ? (s >= 1) : (s < TT);
        if (active) {
            const int rd = (s + 1) & 1;
            const float* __restrict__ h0rd = h0T + (size_t)rd * HB;
            float acc[16];
#pragma unroll
            for (int r = 0; r < 16; ++r) acc[r] = 0.0f;

            if (!isL1) {
                const int k0 = wv * 48;
                int k1 = k0 + 48; if (k1 > K0) k1 = K0;
                {   // feats segment
                    const float* __restrict__ vf = featsT + (size_t)s * NB + b;
                    const int e = (k1 < NN) ? k1 : NN;
#pragma unroll 4
                    for (int k = k0; k < e; ++k) {
                        const float vv = vf[(size_t)k * 64];
                        FMA16(k, vv)
                    }
                }
                {   // recurrent segment
                    const float* __restrict__ vh = h0rd + b;
                    const int st = (k0 > NN) ? k0 : NN;
#pragma unroll 4
                    for (int k = st; k < k1; ++k) {
                        const float vv = vh[(size_t)(k - NN) * 64];
                        FMA16(k, vv)
                    }
                }
            } else {
                const int k0 = wv * 64;
                if (k0 < HH) {  // input segment = h0 current wavefront
                    const float* __restrict__ vh = h0rd + b;
#pragma unroll 4
                    for (int kk = 0; kk < 64; ++kk) {
                        const int k = k0 + kk;
                        const float vv = vh[(size_t)k * 64];
                        FMA16(k, vv)
                    }
                } else {        // recurrent segment = h1 prev
                    const float* __restrict__ vh = h1T + (size_t)rd * HB + b;
#pragma unroll 4
                    for (int kk = 0; kk < 64; ++kk) {
                        const int k = k0 + kk;
                        const float vv = vh[(size_t)(k - HH) * 64];
                        FMA16(k, vv)
                    }
                }
            }

#pragma unroll
            for (int r = 0; r < 16; ++r) part[(wv * 16 + r) * 64 + b] = acc[r];
            __syncthreads();

            if (wv < 4) {
                float g4[4];
#pragma unroll
                for (int g = 0; g < 4; ++g) {
                    float sum = bsum[g];
#pragma unroll
                    for (int i = 0; i < 16; ++i) sum += part[(i * 16 + wv * 4 + g) * 64 + b];
                    g4[g] = sum;
                }
                const float gi = sigmoidf_(g4[0]);
                const float gf = sigmoidf_(g4[1]);
                const float gg = tanhf(g4[2]);
                const float go = sigmoidf_(g4[3]);
                const int hu = bi * 4 + wv;
                float* __restrict__ cT = isL1 ? c1T : c0T;
                const float cp = cT[hu * 64 + b];
                const float cn = fmaf(gf, cp, gi * gg);
                cT[hu * 64 + b] = cn;
                float* __restrict__ hT = (isL1 ? h1T : h0T) + (size_t)(s & 1) * HB;
                hT[hu * 64 + b] = go * tanhf(cn);
            }
        }
        // ---- grid barrier (2-level sense-reversing, target = s+1) ----
        __syncthreads();
        if (tid == 0) {
            const unsigned target = (unsigned)(s + 1);
            if (__hip_atomic_fetch_add(leaf, 1u, __ATOMIC_ACQ_REL, AGENT) == 7u) {
                __hip_atomic_store(leaf, 0u, __ATOMIC_RELAXED, AGENT);
                if (__hip_atomic_fetch_add(root, 1u, __ATOMIC_ACQ_REL, AGENT) == 31u) {
                    __hip_atomic_store(root, 0u, __ATOMIC_RELAXED, AGENT);
                    __hip_atomic_fetch_add(gen, 1u, __ATOMIC_ACQ_REL, AGENT);
                } else {
                    while (__hip_atomic_load(gen, __ATOMIC_ACQUIRE, AGENT) < target)
                        __builtin_amdgcn_s_sleep(1);
                }
                __hip_atomic_fetch_add(ggen, 1u, __ATOMIC_ACQ_REL, AGENT);
            } else {
                while (__hip_atomic_load(ggen, __ATOMIC_ACQUIRE, AGENT) < target)
                    __builtin_amdgcn_s_sleep(1);
            }
        }
        __syncthreads();
    }
#undef FMA16
}

// ---------------- head: out[b][o] = relu(sum_k h1T[k][b]*Wout[o][k] + bout[o]) ----------
__global__ __launch_bounds__(256) void k_out(const float* __restrict__ h1T,
                                             const float* __restrict__ Wout,
                                             const float* __restrict__ bout,
                                             float* __restrict__ out) {
    const int o = blockIdx.x * 4 + (threadIdx.x >> 6);
    const int b = threadIdx.x & 63;
    float acc = 0.0f;
    const float* wrow = Wout + (size_t)o * HH;
    for (int k = 0; k < HH; k += 4) {
        const float4 wv = *reinterpret_cast<const float4*>(wrow + k);
        acc = fmaf(wv.x, h1T[(k + 0) * BB + b],
              fmaf(wv.y, h1T[(k + 1) * BB + b],
              fmaf(wv.z, h1T[(k + 2) * BB + b],
              fmaf(wv.w, h1T[(k + 3) * BB + b], acc))));
    }
    acc += bout[o];
    out[(size_t)b * 1024 + o] = fmaxf(acc, 0.0f);
}

extern "C" void kernel_launch(void* const* d_in, const int* in_sizes, int n_in,
                              void* d_out, int out_size, void* d_ws, size_t ws_size,
                              hipStream_t stream) {
    (void)in_sizes; (void)n_in; (void)out_size; (void)ws_size;
    const float* x    = (const float*)d_in[0];
    const float* Wih0 = (const float*)d_in[1];
    const float* Whh0 = (const float*)d_in[2];
    const float* bih0 = (const float*)d_in[3];
    const float* bhh0 = (const float*)d_in[4];
    const float* Wih1 = (const float*)d_in[5];
    const float* Whh1 = (const float*)d_in[6];
    const float* bih1 = (const float*)d_in[7];
    const float* bhh1 = (const float*)d_in[8];
    const float* Wout = (const float*)d_in[9];
    const float* bout = (const float*)d_in[10];

    float* ws     = (float*)d_ws;
    float* xT     = ws;                          // 8,192,000 floats (dead after caputo)
    float* WT0b   = ws;                          // aliases xT: 128*762*16  = 1,560,576
    float* WT1b   = WT0b + (size_t)128 * K0 * 16;//             128*1024*16 = 2,097,152
    float* featsT = xT + (size_t)TT * NB;        // 8,192,000
    float* w      = featsT + (size_t)TT * NB;    // 512
    float* rowsum = w + TT;                      // 512
    float* h0T    = rowsum + TT;                 // 2*HB
    float* c0T    = h0T + 2 * (size_t)HB;        // HB
    float* h1T    = c0T + (size_t)HB;            // 2*HB
    float* c1T    = h1T + 2 * (size_t)HB;        // HB
    unsigned* bar = (unsigned*)(c1T + (size_t)HB); // 4096 u32 barrier region

    // zero LSTM state (6*HB floats) + barrier counters
    hipMemsetAsync(h0T, 0, (size_t)6 * HB * sizeof(float), stream);
    hipMemsetAsync(bar, 0, 4096 * sizeof(unsigned), stream);

    k_transpose<<<dim3(TT, 63), 256, 0, stream>>>(x, xT);
    k_wrow<<<1, TT, 0, stream>>>(w, rowsum);
    k_caputo<<<dim3(TT / 4, 16), 256, 0, stream>>>(xT, w, rowsum, featsT);
    // xT dead now; build transposed weights over it
    k_wt<<<512, 256, 0, stream>>>(Wih0, Whh0, Wih1, Whh1, WT0b, WT1b);

    void* args[] = {(void*)&featsT, (void*)&WT0b, (void*)&WT1b,
                    (void*)&bih0, (void*)&bhh0, (void*)&bih1, (void*)&bhh1,
                    (void*)&h0T, (void*)&c0T, (void*)&h1T, (void*)&c1T, (void*)&bar};
    hipLaunchCooperativeKernel((void*)k_persist, dim3(256), dim3(1024), args, 0, stream);

    k_out<<<256, 256, 0, stream>>>(h1T, Wout, bout, (float*)d_out);
}

// Round 5
// 13216.072 us; speedup vs baseline: 1.8599x; 1.8599x over previous
//
#include <hip/hip_runtime.h>
#include <cstddef>

#define BB 64      // batch
#define TT 512     // time steps
#define NN 250     // useful input features (alpha=1.0 block is zero)
#define HH 512     // hidden
#define NB (NN*BB) // 16000 floats per timestep slice
#define HB (HH*BB) // 32768 floats per hidden state
#define K0 762     // layer0 dot length: 250 feats + 512 recurrent
#define K1 1024    // layer1 dot length: 512 input + 512 recurrent

__device__ __forceinline__ float sigmoidf_(float x) { return 1.0f / (1.0f + expf(-x)); }

// ---------------- transpose x[b][t][n] -> xT[t][n][b] ----------------
__global__ __launch_bounds__(256) void k_transpose(const float* __restrict__ x,
                                                   float* __restrict__ xT) {
    const int t = blockIdx.x;
    const int n = blockIdx.y * 4 + (threadIdx.x >> 6);
    const int b = threadIdx.x & 63;
    if (n < NN)
        xT[(size_t)t * NB + n * BB + b] = x[(size_t)b * (TT * NN) + t * NN + n];
}

// ---------------- w[d] = (d+1e-6)^-0.5, rowsum[t] = sum_{d=1..t} w[d] ----------------
__global__ __launch_bounds__(512) void k_wrow(float* __restrict__ w, float* __restrict__ rowsum) {
    __shared__ float sw[TT];
    const int d = threadIdx.x;
    const float wd = (d >= 1) ? (1.0f / sqrtf((float)d + 1e-6f)) : 0.0f;
    sw[d] = wd;
    w[d] = wd;
    __syncthreads();
    float s = 0.0f;
    for (int j = 1; j <= d; ++j) s += sw[j];
    rowsum[d] = s;
}

// ---------------- caputo: featsT[t][n][b] = coef*(x*rowsum[t] - sum_{j<t} w[t-j]*x[j]) ----
__global__ __launch_bounds__(256) void k_caputo(const float* __restrict__ xT,
                                                const float* __restrict__ w,
                                                const float* __restrict__ rowsum,
                                                float* __restrict__ featsT) {
    const float COEF = 0.5641895835477563f;  // 1/gamma(0.5)
    const int t0 = blockIdx.x * 4;
    const int nb0 = blockIdx.y * 1024 + threadIdx.x;
    float acc[4][4];
#pragma unroll
    for (int a = 0; a < 4; ++a)
#pragma unroll
        for (int e = 0; e < 4; ++e) acc[a][e] = 0.0f;

    for (int j = 0; j < t0; ++j) {
        const float* xj = xT + (size_t)j * NB;
        const float wt0 = w[t0 - j];
        const float wt1 = w[t0 + 1 - j];
        const float wt2 = w[t0 + 2 - j];
        const float wt3 = w[t0 + 3 - j];
#pragma unroll
        for (int e = 0; e < 4; ++e) {
            const int nb = nb0 + e * 256;
            const float xv = (nb < NB) ? xj[nb] : 0.0f;
            acc[0][e] = fmaf(wt0, xv, acc[0][e]);
            acc[1][e] = fmaf(wt1, xv, acc[1][e]);
            acc[2][e] = fmaf(wt2, xv, acc[2][e]);
            acc[3][e] = fmaf(wt3, xv, acc[3][e]);
        }
    }
#pragma unroll
    for (int dj = 0; dj < 3; ++dj) {
        const int j = t0 + dj;
        const float* xj = xT + (size_t)j * NB;
#pragma unroll
        for (int e = 0; e < 4; ++e) {
            const int nb = nb0 + e * 256;
            const float xv = (nb < NB) ? xj[nb] : 0.0f;
#pragma unroll
            for (int tt = 0; tt < 4; ++tt)
                if (tt > dj) acc[tt][e] = fmaf(w[tt - dj], xv, acc[tt][e]);
        }
    }
#pragma unroll
    for (int tt = 0; tt < 4; ++tt) {
        const int t = t0 + tt;
        const float rs = rowsum[t];
        const float* xt = xT + (size_t)t * NB;
        float* ft = featsT + (size_t)t * NB;
#pragma unroll
        for (int e = 0; e < 4; ++e) {
            const int nb = nb0 + e * 256;
            if (nb < NB) ft[nb] = COEF * fmaf(xt[nb], rs, -acc[tt][e]);
        }
    }
}

// ---------------- weight transpose: WT[bi][k][r], r = hu_local*4 + gate ----------------
__global__ __launch_bounds__(256) void k_wt(const float* __restrict__ Wih0,
                                            const float* __restrict__ Whh0,
                                            const float* __restrict__ Wih1,
                                            const float* __restrict__ Whh1,
                                            float* __restrict__ WT0b,
                                            float* __restrict__ WT1b) {
    const int total0 = 128 * K0 * 16;
    const int total1 = 128 * K1 * 16;
    const int stride = gridDim.x * 256;
    for (int idx = blockIdx.x * 256 + threadIdx.x; idx < total0; idx += stride) {
        const int r = idx & 15;
        const int k = (idx >> 4) % K0;
        const int bi = idx / (16 * K0);
        const int row = (r & 3) * HH + bi * 4 + (r >> 2);
        WT0b[idx] = (k < NN) ? Wih0[(size_t)row * 500 + k] : Whh0[(size_t)row * HH + (k - NN)];
    }
    for (int idx = blockIdx.x * 256 + threadIdx.x; idx < total1; idx += stride) {
        const int r = idx & 15;
        const int k = (idx >> 4) % K1;
        const int bi = idx / (16 * K1);
        const int row = (r & 3) * HH + bi * 4 + (r >> 2);
        WT1b[idx] = (k < HH) ? Wih1[(size_t)row * HH + k] : Whh1[(size_t)row * HH + (k - HH)];
    }
}

// ---------------- persistent LSTM ----------------
#define AGENT __HIP_MEMORY_SCOPE_AGENT

// Grid barrier: RELAXED spins (no cache maintenance per poll), RELEASE only at
// arrival (one buffer_wbl2 flushing this block's dirty h-lines), ONE ACQUIRE
// after spin-exit (one buffer_inv so post-barrier reads see fresh h).
__device__ __forceinline__ void gridbar(unsigned* leaf, unsigned* ggen,
                                        unsigned* root, unsigned* gen,
                                        unsigned target, int tid) {
    __syncthreads();   // all waves' h-stores drained to L2 (waitcnt before s_barrier)
    if (tid == 0) {
        if (__hip_atomic_fetch_add(leaf, 1u, __ATOMIC_RELEASE, AGENT) == 7u) {
            __hip_atomic_store(leaf, 0u, __ATOMIC_RELAXED, AGENT);
            if (__hip_atomic_fetch_add(root, 1u, __ATOMIC_RELAXED, AGENT) == 31u) {
                __hip_atomic_store(root, 0u, __ATOMIC_RELAXED, AGENT);
                __hip_atomic_fetch_add(gen, 1u, __ATOMIC_RELAXED, AGENT);
            } else {
                while (__hip_atomic_load(gen, __ATOMIC_RELAXED, AGENT) < target)
                    __builtin_amdgcn_s_sleep(1);
            }
            __hip_atomic_fetch_add(ggen, 1u, __ATOMIC_RELAXED, AGENT);
        } else {
            while (__hip_atomic_load(ggen, __ATOMIC_RELAXED, AGENT) < target)
                __builtin_amdgcn_s_sleep(1);
        }
        (void)__hip_atomic_load(gen, __ATOMIC_ACQUIRE, AGENT);  // single L2 inv
    }
    __syncthreads();
}

__global__ __launch_bounds__(1024, 4) void k_persist(
    const float* __restrict__ featsT,
    const float* __restrict__ WT0b, const float* __restrict__ WT1b,
    const float* __restrict__ bih0, const float* __restrict__ bhh0,
    const float* __restrict__ bih1, const float* __restrict__ bhh1,
    float* __restrict__ h0T, float* __restrict__ h1T,
    unsigned* __restrict__ bar) {
    __shared__ float wlds[16384];       // 64KB weight slice
    __shared__ float part[16384];       // 64KB partials [wave][row][lane]
    const int tid = threadIdx.x;
    const int b = tid & 63;
    const int wv = tid >> 6;
    const int bid = blockIdx.x;
    const bool isL1 = (bid >= 128);
    const int bi = isL1 ? (bid - 128) : bid;

    unsigned* leaf = bar + (bid >> 3) * 32;
    unsigned* ggen = bar + 1024 + (bid >> 3) * 32;
    unsigned* root = bar + 2048;
    unsigned* gen  = bar + 2080;

    // ---- stage weights into LDS once ----
    {
        const float* __restrict__ wsrc = isL1 ? (WT1b + (size_t)bi * (K1 * 16))
                                              : (WT0b + (size_t)bi * (K0 * 16));
        const int nflt = (isL1 ? K1 : K0) * 16;
        for (int i = tid * 4; i < nflt; i += 4096)
            *reinterpret_cast<float4*>(&wlds[i]) = *reinterpret_cast<const float4*>(wsrc + i);
    }
    // ---- hoist bias sums; cell state lives in registers (never crosses blocks) ----
    float bsum[4] = {0.f, 0.f, 0.f, 0.f};
    float creg = 0.0f;
    if (wv < 4) {
        const int hu = bi * 4 + wv;
        const float* __restrict__ bi_ = isL1 ? bih1 : bih0;
        const float* __restrict__ bh_ = isL1 ? bhh1 : bhh0;
#pragma unroll
        for (int g = 0; g < 4; ++g) bsum[g] = bi_[g * HH + hu] + bh_[g * HH + hu];
    }
    __syncthreads();

#define FMA16(KIDX, VV)                                                         \
    {                                                                           \
        const float4* wl = reinterpret_cast<const float4*>(&wlds[(KIDX) * 16]); \
        const float4 w0_ = wl[0], w1_ = wl[1], w2_ = wl[2], w3_ = wl[3];        \
        acc[0] = fmaf(w0_.x, (VV), acc[0]);   acc[1] = fmaf(w0_.y, (VV), acc[1]);  \
        acc[2] = fmaf(w0_.z, (VV), acc[2]);   acc[3] = fmaf(w0_.w, (VV), acc[3]);  \
        acc[4] = fmaf(w1_.x, (VV), acc[4]);   acc[5] = fmaf(w1_.y, (VV), acc[5]);  \
        acc[6] = fmaf(w1_.z, (VV), acc[6]);   acc[7] = fmaf(w1_.w, (VV), acc[7]);  \
        acc[8] = fmaf(w2_.x, (VV), acc[8]);   acc[9] = fmaf(w2_.y, (VV), acc[9]);  \
        acc[10] = fmaf(w2_.z, (VV), acc[10]); acc[11] = fmaf(w2_.w, (VV), acc[11]); \
        acc[12] = fmaf(w3_.x, (VV), acc[12]); acc[13] = fmaf(w3_.y, (VV), acc[13]); \
        acc[14] = fmaf(w3_.z, (VV), acc[14]); acc[15] = fmaf(w3_.w, (VV), acc[15]); \
    }

    for (int s = 0; s <= TT; ++s) {
        const bool active = isL1 ? (s >= 1) : (s < TT);
        if (active) {
            const int rd = (s + 1) & 1;
            const float* __restrict__ h0rd = h0T + (size_t)rd * HB;
            float acc[16];
#pragma unroll
            for (int r = 0; r < 16; ++r) acc[r] = 0.0f;

            if (!isL1) {
                const int k0 = wv * 48;
                int k1 = k0 + 48; if (k1 > K0) k1 = K0;
                {   // feats segment
                    const float* __restrict__ vf = featsT + (size_t)s * NB + b;
                    const int e = (k1 < NN) ? k1 : NN;
#pragma unroll 8
                    for (int k = k0; k < e; ++k) {
                        const float vv = vf[(size_t)k * 64];
                        FMA16(k, vv)
                    }
                }
                {   // recurrent segment
                    const float* __restrict__ vh = h0rd + b;
                    const int st = (k0 > NN) ? k0 : NN;
#pragma unroll 8
                    for (int k = st; k < k1; ++k) {
                        const float vv = vh[(size_t)(k - NN) * 64];
                        FMA16(k, vv)
                    }
                }
            } else {
                const int k0 = wv * 64;
                if (k0 < HH) {  // input segment = h0 current wavefront
                    const float* __restrict__ vh = h0rd + b;
#pragma unroll 8
                    for (int kk = 0; kk < 64; ++kk) {
                        const int k = k0 + kk;
                        const float vv = vh[(size_t)k * 64];
                        FMA16(k, vv)
                    }
                } else {        // recurrent segment = h1 prev
                    const float* __restrict__ vh = h1T + (size_t)rd * HB + b;
#pragma unroll 8
                    for (int kk = 0; kk < 64; ++kk) {
                        const int k = k0 + kk;
                        const float vv = vh[(size_t)(k - HH) * 64];
                        FMA16(k, vv)
                    }
                }
            }

#pragma unroll
            for (int r = 0; r < 16; ++r) part[(wv * 16 + r) * 64 + b] = acc[r];
            __syncthreads();

            if (wv < 4) {
                float g4[4];
#pragma unroll
                for (int g = 0; g < 4; ++g) {
                    float sum = bsum[g];
#pragma unroll
                    for (int i = 0; i < 16; ++i) sum += part[(i * 16 + wv * 4 + g) * 64 + b];
                    g4[g] = sum;
                }
                const float gi = sigmoidf_(g4[0]);
                const float gf = sigmoidf_(g4[1]);
                const float gg = tanhf(g4[2]);
                const float go = sigmoidf_(g4[3]);
                const float cn = fmaf(gf, creg, gi * gg);
                creg = cn;
                const int hu = bi * 4 + wv;
                float* __restrict__ hT = (isL1 ? h1T : h0T) + (size_t)(s & 1) * HB;
                hT[hu * 64 + b] = go * tanhf(cn);
            }
        }
        gridbar(leaf, ggen, root, gen, (unsigned)(s + 1), tid);
    }
#undef FMA16
}

// ---------------- head: out[b][o] = relu(sum_k h1T[k][b]*Wout[o][k] + bout[o]) ----------
__global__ __launch_bounds__(256) void k_out(const float* __restrict__ h1T,
                                             const float* __restrict__ Wout,
                                             const float* __restrict__ bout,
                                             float* __restrict__ out) {
    const int o = blockIdx.x * 4 + (threadIdx.x >> 6);
    const int b = threadIdx.x & 63;
    float acc = 0.0f;
    const float* wrow = Wout + (size_t)o * HH;
    for (int k = 0; k < HH; k += 4) {
        const float4 wv = *reinterpret_cast<const float4*>(wrow + k);
        acc = fmaf(wv.x, h1T[(k + 0) * BB + b],
              fmaf(wv.y, h1T[(k + 1) * BB + b],
              fmaf(wv.z, h1T[(k + 2) * BB + b],
              fmaf(wv.w, h1T[(k + 3) * BB + b], acc))));
    }
    acc += bout[o];
    out[(size_t)b * 1024 + o] = fmaxf(acc, 0.0f);
}

extern "C" void kernel_launch(void* const* d_in, const int* in_sizes, int n_in,
                              void* d_out, int out_size, void* d_ws, size_t ws_size,
                              hipStream_t stream) {
    (void)in_sizes; (void)n_in; (void)out_size; (void)ws_size;
    const float* x    = (const float*)d_in[0];
    const float* Wih0 = (const float*)d_in[1];
    const float* Whh0 = (const float*)d_in[2];
    const float* bih0 = (const float*)d_in[3];
    const float* bhh0 = (const float*)d_in[4];
    const float* Wih1 = (const float*)d_in[5];
    const float* Whh1 = (const float*)d_in[6];
    const float* bih1 = (const float*)d_in[7];
    const float* bhh1 = (const float*)d_in[8];
    const float* Wout = (const float*)d_in[9];
    const float* bout = (const float*)d_in[10];

    float* ws     = (float*)d_ws;
    float* xT     = ws;                          // 8,192,000 floats (dead after caputo)
    float* WT0b   = ws;                          // aliases xT: 128*762*16  = 1,560,576
    float* WT1b   = WT0b + (size_t)128 * K0 * 16;//             128*1024*16 = 2,097,152
    float* featsT = xT + (size_t)TT * NB;        // 8,192,000
    float* w      = featsT + (size_t)TT * NB;    // 512
    float* rowsum = w + TT;                      // 512
    float* h0T    = rowsum + TT;                 // 2*HB
    float* h1T    = h0T + 2 * (size_t)HB;        // 2*HB
    unsigned* bar = (unsigned*)(h1T + 2 * (size_t)HB); // 4096 u32 barrier region

    // zero h double-buffers + barrier counters
    hipMemsetAsync(h0T, 0, (size_t)4 * HB * sizeof(float), stream);
    hipMemsetAsync(bar, 0, 4096 * sizeof(unsigned), stream);

    k_transpose<<<dim3(TT, 63), 256, 0, stream>>>(x, xT);
    k_wrow<<<1, TT, 0, stream>>>(w, rowsum);
    k_caputo<<<dim3(TT / 4, 16), 256, 0, stream>>>(xT, w, rowsum, featsT);
    // xT dead now; build transposed weights over it
    k_wt<<<512, 256, 0, stream>>>(Wih0, Whh0, Wih1, Whh1, WT0b, WT1b);

    void* args[] = {(void*)&featsT, (void*)&WT0b, (void*)&WT1b,
                    (void*)&bih0, (void*)&bhh0, (void*)&bih1, (void*)&bhh1,
                    (void*)&h0T, (void*)&h1T, (void*)&bar};
    hipLaunchCooperativeKernel((void*)k_persist, dim3(256), dim3(1024), args, 0, stream);

    k_out<<<256, 256, 0, stream>>>(h1T, Wout, bout, (float*)d_out);
}

// Round 6
// 6577.174 us; speedup vs baseline: 3.7372x; 2.0094x over previous
//
#include <hip/hip_runtime.h>
#include <cstddef>

#define BB 64      // batch
#define TT 512     // time steps
#define NN 250     // useful input features (alpha=1.0 block is zero)
#define HH 512     // hidden
#define NB (NN*BB) // 16000 floats per timestep slice
#define HB (HH*BB) // 32768 floats per hidden state
#define K0 762     // layer0 dot length: 250 feats + 512 recurrent
#define K1 1024    // layer1 dot length: 512 input + 512 recurrent

#define AGENT __HIP_MEMORY_SCOPE_AGENT

__device__ __forceinline__ float sigmoidf_(float x) { return 1.0f / (1.0f + expf(-x)); }

// Coherent (L2-bypassing, device-scope) element access for cross-block h-state.
// RELAXED => no buffer_wbl2 / buffer_inv cache maintenance is emitted.
__device__ __forceinline__ float coh_ld(const float* p) {
    return __hip_atomic_load(p, __ATOMIC_RELAXED, AGENT);
}
__device__ __forceinline__ void coh_st(float* p, float v) {
    __hip_atomic_store(p, v, __ATOMIC_RELAXED, AGENT);
}

// ---------------- transpose x[b][t][n] -> xT[t][n][b] ----------------
__global__ __launch_bounds__(256) void k_transpose(const float* __restrict__ x,
                                                   float* __restrict__ xT) {
    const int t = blockIdx.x;
    const int n = blockIdx.y * 4 + (threadIdx.x >> 6);
    const int b = threadIdx.x & 63;
    if (n < NN)
        xT[(size_t)t * NB + n * BB + b] = x[(size_t)b * (TT * NN) + t * NN + n];
}

// ---------------- w[d] = (d+1e-6)^-0.5, rowsum[t] = sum_{d=1..t} w[d] ----------------
__global__ __launch_bounds__(512) void k_wrow(float* __restrict__ w, float* __restrict__ rowsum) {
    __shared__ float sw[TT];
    const int d = threadIdx.x;
    const float wd = (d >= 1) ? (1.0f / sqrtf((float)d + 1e-6f)) : 0.0f;
    sw[d] = wd;
    w[d] = wd;
    __syncthreads();
    float s = 0.0f;
    for (int j = 1; j <= d; ++j) s += sw[j];
    rowsum[d] = s;
}

// ---------------- caputo: featsT[t][n][b] = coef*(x*rowsum[t] - sum_{j<t} w[t-j]*x[j]) ----
__global__ __launch_bounds__(256) void k_caputo(const float* __restrict__ xT,
                                                const float* __restrict__ w,
                                                const float* __restrict__ rowsum,
                                                float* __restrict__ featsT) {
    const float COEF = 0.5641895835477563f;  // 1/gamma(0.5)
    const int t0 = blockIdx.x * 4;
    const int nb0 = blockIdx.y * 1024 + threadIdx.x;
    float acc[4][4];
#pragma unroll
    for (int a = 0; a < 4; ++a)
#pragma unroll
        for (int e = 0; e < 4; ++e) acc[a][e] = 0.0f;

    for (int j = 0; j < t0; ++j) {
        const float* xj = xT + (size_t)j * NB;
        const float wt0 = w[t0 - j];
        const float wt1 = w[t0 + 1 - j];
        const float wt2 = w[t0 + 2 - j];
        const float wt3 = w[t0 + 3 - j];
#pragma unroll
        for (int e = 0; e < 4; ++e) {
            const int nb = nb0 + e * 256;
            const float xv = (nb < NB) ? xj[nb] : 0.0f;
            acc[0][e] = fmaf(wt0, xv, acc[0][e]);
            acc[1][e] = fmaf(wt1, xv, acc[1][e]);
            acc[2][e] = fmaf(wt2, xv, acc[2][e]);
            acc[3][e] = fmaf(wt3, xv, acc[3][e]);
        }
    }
#pragma unroll
    for (int dj = 0; dj < 3; ++dj) {
        const int j = t0 + dj;
        const float* xj = xT + (size_t)j * NB;
#pragma unroll
        for (int e = 0; e < 4; ++e) {
            const int nb = nb0 + e * 256;
            const float xv = (nb < NB) ? xj[nb] : 0.0f;
#pragma unroll
            for (int tt = 0; tt < 4; ++tt)
                if (tt > dj) acc[tt][e] = fmaf(w[tt - dj], xv, acc[tt][e]);
        }
    }
#pragma unroll
    for (int tt = 0; tt < 4; ++tt) {
        const int t = t0 + tt;
        const float rs = rowsum[t];
        const float* xt = xT + (size_t)t * NB;
        float* ft = featsT + (size_t)t * NB;
#pragma unroll
        for (int e = 0; e < 4; ++e) {
            const int nb = nb0 + e * 256;
            if (nb < NB) ft[nb] = COEF * fmaf(xt[nb], rs, -acc[tt][e]);
        }
    }
}

// ---------------- weight transpose: WT[bi][k][r], r = hu_local*4 + gate ----------------
__global__ __launch_bounds__(256) void k_wt(const float* __restrict__ Wih0,
                                            const float* __restrict__ Whh0,
                                            const float* __restrict__ Wih1,
                                            const float* __restrict__ Whh1,
                                            float* __restrict__ WT0b,
                                            float* __restrict__ WT1b) {
    const int total0 = 128 * K0 * 16;
    const int total1 = 128 * K1 * 16;
    const int stride = gridDim.x * 256;
    for (int idx = blockIdx.x * 256 + threadIdx.x; idx < total0; idx += stride) {
        const int r = idx & 15;
        const int k = (idx >> 4) % K0;
        const int bi = idx / (16 * K0);
        const int row = (r & 3) * HH + bi * 4 + (r >> 2);
        WT0b[idx] = (k < NN) ? Wih0[(size_t)row * 500 + k] : Whh0[(size_t)row * HH + (k - NN)];
    }
    for (int idx = blockIdx.x * 256 + threadIdx.x; idx < total1; idx += stride) {
        const int r = idx & 15;
        const int k = (idx >> 4) % K1;
        const int bi = idx / (16 * K1);
        const int row = (r & 3) * HH + bi * 4 + (r >> 2);
        WT1b[idx] = (k < HH) ? Wih1[(size_t)row * HH + k] : Whh1[(size_t)row * HH + (k - HH)];
    }
}

// ---------------- grid barrier: ALL relaxed, zero cache maintenance ----------------
// Correctness: h-stores are sc1 (coherent at L3) and are drained by the
// vmcnt(0) the compiler emits for __syncthreads() before tid0's flag add;
// readers poll coherent flags and read h with coherent loads.
__device__ __forceinline__ void gridbar(unsigned* leaf, unsigned* ggen,
                                        unsigned* root, unsigned* gen,
                                        unsigned target, int tid) {
    __syncthreads();
    if (tid == 0) {
        if (__hip_atomic_fetch_add(leaf, 1u, __ATOMIC_RELAXED, AGENT) == 7u) {
            __hip_atomic_store(leaf, 0u, __ATOMIC_RELAXED, AGENT);
            if (__hip_atomic_fetch_add(root, 1u, __ATOMIC_RELAXED, AGENT) == 31u) {
                __hip_atomic_store(root, 0u, __ATOMIC_RELAXED, AGENT);
                __hip_atomic_fetch_add(gen, 1u, __ATOMIC_RELAXED, AGENT);
            } else {
                while (__hip_atomic_load(gen, __ATOMIC_RELAXED, AGENT) < target)
                    __builtin_amdgcn_s_sleep(1);
            }
            __hip_atomic_fetch_add(ggen, 1u, __ATOMIC_RELAXED, AGENT);
        } else {
            while (__hip_atomic_load(ggen, __ATOMIC_RELAXED, AGENT) < target)
                __builtin_amdgcn_s_sleep(1);
        }
    }
    __syncthreads();
}

// ---------------- persistent LSTM: all 513 wavefront steps in one launch ----------------
__global__ __launch_bounds__(1024, 4) void k_persist(
    const float* __restrict__ featsT,
    const float* __restrict__ WT0b, const float* __restrict__ WT1b,
    const float* __restrict__ bih0, const float* __restrict__ bhh0,
    const float* __restrict__ bih1, const float* __restrict__ bhh1,
    float* __restrict__ h0T, float* __restrict__ h1T,
    unsigned* __restrict__ bar) {
    __shared__ float wlds[16384];       // 64KB weight slice (persistent)
    __shared__ float part[16384];       // 64KB partials [wave][row][lane]
    const int tid = threadIdx.x;
    const int b = tid & 63;
    const int wv = tid >> 6;
    const int bid = blockIdx.x;
    const bool isL1 = (bid >= 128);
    const int bi = isL1 ? (bid - 128) : bid;

    unsigned* leaf = bar + (bid >> 3) * 32;
    unsigned* ggen = bar + 1024 + (bid >> 3) * 32;
    unsigned* root = bar + 2048;
    unsigned* gen  = bar + 2080;

    // ---- stage weights into LDS once ----
    {
        const float* __restrict__ wsrc = isL1 ? (WT1b + (size_t)bi * (K1 * 16))
                                              : (WT0b + (size_t)bi * (K0 * 16));
        const int nflt = (isL1 ? K1 : K0) * 16;
        for (int i = tid * 4; i < nflt; i += 4096)
            *reinterpret_cast<float4*>(&wlds[i]) = *reinterpret_cast<const float4*>(wsrc + i);
    }
    // ---- hoist bias sums; cell state in registers (never crosses blocks) ----
    float bsum[4] = {0.f, 0.f, 0.f, 0.f};
    float creg = 0.0f;
    if (wv < 4) {
        const int hu = bi * 4 + wv;
        const float* __restrict__ bi_ = isL1 ? bih1 : bih0;
        const float* __restrict__ bh_ = isL1 ? bhh1 : bhh0;
#pragma unroll
        for (int g = 0; g < 4; ++g) bsum[g] = bi_[g * HH + hu] + bh_[g * HH + hu];
    }
    __syncthreads();

#define FMA16(KIDX, VV)                                                         \
    {                                                                           \
        const float4* wl = reinterpret_cast<const float4*>(&wlds[(KIDX) * 16]); \
        const float4 w0_ = wl[0], w1_ = wl[1], w2_ = wl[2], w3_ = wl[3];        \
        acc[0] = fmaf(w0_.x, (VV), acc[0]);   acc[1] = fmaf(w0_.y, (VV), acc[1]);  \
        acc[2] = fmaf(w0_.z, (VV), acc[2]);   acc[3] = fmaf(w0_.w, (VV), acc[3]);  \
        acc[4] = fmaf(w1_.x, (VV), acc[4]);   acc[5] = fmaf(w1_.y, (VV), acc[5]);  \
        acc[6] = fmaf(w1_.z, (VV), acc[6]);   acc[7] = fmaf(w1_.w, (VV), acc[7]);  \
        acc[8] = fmaf(w2_.x, (VV), acc[8]);   acc[9] = fmaf(w2_.y, (VV), acc[9]);  \
        acc[10] = fmaf(w2_.z, (VV), acc[10]); acc[11] = fmaf(w2_.w, (VV), acc[11]); \
        acc[12] = fmaf(w3_.x, (VV), acc[12]); acc[13] = fmaf(w3_.y, (VV), acc[13]); \
        acc[14] = fmaf(w3_.z, (VV), acc[14]); acc[15] = fmaf(w3_.w, (VV), acc[15]); \
    }

    for (int s = 0; s <= TT; ++s) {
        const bool active = isL1 ? (s >= 1) : (s < TT);
        if (active) {
            const int rd = (s + 1) & 1;
            const float* __restrict__ h0rd = h0T + (size_t)rd * HB;
            float acc[16];
#pragma unroll
            for (int r = 0; r < 16; ++r) acc[r] = 0.0f;

            if (!isL1) {
                const int k0 = wv * 48;
                int k1 = k0 + 48; if (k1 > K0) k1 = K0;
                {   // feats segment (cached loads, chunked)
                    const float* __restrict__ vf = featsT + (size_t)s * NB + b;
                    const int e = (k1 < NN) ? k1 : NN;
                    int k = k0;
                    for (; k + 8 <= e; k += 8) {
                        float v[8];
#pragma unroll
                        for (int j = 0; j < 8; ++j) v[j] = vf[(size_t)(k + j) * 64];
#pragma unroll
                        for (int j = 0; j < 8; ++j) FMA16(k + j, v[j])
                    }
                    for (; k < e; ++k) { const float vv = vf[(size_t)k * 64]; FMA16(k, vv) }
                }
                {   // recurrent segment (coherent loads, chunked 8 for MLP)
                    const float* __restrict__ vh = h0rd + b;
                    const int st = (k0 > NN) ? k0 : NN;
                    int k = st;
                    for (; k + 8 <= k1; k += 8) {
                        float v[8];
#pragma unroll
                        for (int j = 0; j < 8; ++j) v[j] = coh_ld(&vh[(size_t)(k - NN + j) * 64]);
#pragma unroll
                        for (int j = 0; j < 8; ++j) FMA16(k + j, v[j])
                    }
                    for (; k < k1; ++k) { const float vv = coh_ld(&vh[(size_t)(k - NN) * 64]); FMA16(k, vv) }
                }
            } else {
                const int k0 = wv * 64;
                const float* __restrict__ vbase =
                    (k0 < HH) ? (h0rd + b) : (h1T + (size_t)rd * HB + b);
                const int koff = (k0 < HH) ? k0 : (k0 - HH);
#pragma unroll 1
                for (int c = 0; c < 64; c += 8) {
                    float v[8];
#pragma unroll
                    for (int j = 0; j < 8; ++j) v[j] = coh_ld(&vbase[(size_t)(koff + c + j) * 64]);
#pragma unroll
                    for (int j = 0; j < 8; ++j) FMA16(k0 + c + j, v[j])
                }
            }

#pragma unroll
            for (int r = 0; r < 16; ++r) part[(wv * 16 + r) * 64 + b] = acc[r];
            __syncthreads();

            if (wv < 4) {
                float g4[4];
#pragma unroll
                for (int g = 0; g < 4; ++g) {
                    float sum = bsum[g];
#pragma unroll
                    for (int i = 0; i < 16; ++i) sum += part[(i * 16 + wv * 4 + g) * 64 + b];
                    g4[g] = sum;
                }
                const float gi = sigmoidf_(g4[0]);
                const float gf = sigmoidf_(g4[1]);
                const float gg = tanhf(g4[2]);
                const float go = sigmoidf_(g4[3]);
                const float cn = fmaf(gf, creg, gi * gg);
                creg = cn;
                const int hu = bi * 4 + wv;
                float* __restrict__ hT = (isL1 ? h1T : h0T) + (size_t)(s & 1) * HB;
                coh_st(&hT[hu * 64 + b], go * tanhf(cn));
            }
        }
        gridbar(leaf, ggen, root, gen, (unsigned)(s + 1), tid);
    }
#undef FMA16
}

// ---------------- head: out[b][o] = relu(sum_k h1T[k][b]*Wout[o][k] + bout[o]) ----------
__global__ __launch_bounds__(256) void k_out(const float* __restrict__ h1T,
                                             const float* __restrict__ Wout,
                                             const float* __restrict__ bout,
                                             float* __restrict__ out) {
    const int o = blockIdx.x * 4 + (threadIdx.x >> 6);
    const int b = threadIdx.x & 63;
    float acc = 0.0f;
    const float* wrow = Wout + (size_t)o * HH;
    for (int k = 0; k < HH; k += 4) {
        const float4 wv = *reinterpret_cast<const float4*>(wrow + k);
        acc = fmaf(wv.x, h1T[(k + 0) * BB + b],
              fmaf(wv.y, h1T[(k + 1) * BB + b],
              fmaf(wv.z, h1T[(k + 2) * BB + b],
              fmaf(wv.w, h1T[(k + 3) * BB + b], acc))));
    }
    acc += bout[o];
    out[(size_t)b * 1024 + o] = fmaxf(acc, 0.0f);
}

extern "C" void kernel_launch(void* const* d_in, const int* in_sizes, int n_in,
                              void* d_out, int out_size, void* d_ws, size_t ws_size,
                              hipStream_t stream) {
    (void)in_sizes; (void)n_in; (void)out_size; (void)ws_size;
    const float* x    = (const float*)d_in[0];
    const float* Wih0 = (const float*)d_in[1];
    const float* Whh0 = (const float*)d_in[2];
    const float* bih0 = (const float*)d_in[3];
    const float* bhh0 = (const float*)d_in[4];
    const float* Wih1 = (const float*)d_in[5];
    const float* Whh1 = (const float*)d_in[6];
    const float* bih1 = (const float*)d_in[7];
    const float* bhh1 = (const float*)d_in[8];
    const float* Wout = (const float*)d_in[9];
    const float* bout = (const float*)d_in[10];

    float* ws     = (float*)d_ws;
    float* xT     = ws;                          // 8,192,000 floats (dead after caputo)
    float* WT0b   = ws;                          // aliases xT: 128*762*16  = 1,560,576
    float* WT1b   = WT0b + (size_t)128 * K0 * 16;//             128*1024*16 = 2,097,152
    float* featsT = xT + (size_t)TT * NB;        // 8,192,000
    float* w      = featsT + (size_t)TT * NB;    // 512
    float* rowsum = w + TT;                      // 512
    float* h0T    = rowsum + TT;                 // 2*HB
    float* h1T    = h0T + 2 * (size_t)HB;        // 2*HB
    unsigned* bar = (unsigned*)(h1T + 2 * (size_t)HB); // 4096 u32 barrier region

    // zero h double-buffers + barrier counters
    hipMemsetAsync(h0T, 0, (size_t)4 * HB * sizeof(float), stream);
    hipMemsetAsync(bar, 0, 4096 * sizeof(unsigned), stream);

    k_transpose<<<dim3(TT, 63), 256, 0, stream>>>(x, xT);
    k_wrow<<<1, TT, 0, stream>>>(w, rowsum);
    k_caputo<<<dim3(TT / 4, 16), 256, 0, stream>>>(xT, w, rowsum, featsT);
    // xT dead now; build transposed weights over it
    k_wt<<<512, 256, 0, stream>>>(Wih0, Whh0, Wih1, Whh1, WT0b, WT1b);

    void* args[] = {(void*)&featsT, (void*)&WT0b, (void*)&WT1b,
                    (void*)&bih0, (void*)&bhh0, (void*)&bih1, (void*)&bhh1,
                    (void*)&h0T, (void*)&h1T, (void*)&bar};
    hipLaunchCooperativeKernel((void*)k_persist, dim3(256), dim3(1024), args, 0, stream);

    k_out<<<256, 256, 0, stream>>>(h1T, Wout, bout, (float*)d_out);
}